// Round 1
// baseline (338.073 us; speedup 1.0000x reference)
//
#include <hip/hip_runtime.h>

#define BATCH   4096
#define SLOTS   26
#define MAX_NNZ 10
#define EMB     64
#define ROWS    (BATCH * SLOTS)   // 106,496 output rows

typedef float floatx2 __attribute__((ext_vector_type(2)));

// One output row [EMB=64 floats] is handled by 32 lanes, each owning one
// float2. A 64-lane wave processes 2 rows concurrently.
//
// Register-diet layout targeting <=64 VGPR -> 8 waves/SIMD (vs ~4 before):
//   - v[10] as float2   = 20 VGPRs (was 40 as float4)
//   - gather addresses as 32-bit byte offsets into the 256MB table,
//     consumed via saddr+voffset form (10 VGPRs, was 20 for 64-bit pairs)
//   - no per-j weights: masked gathers are redirected to table row 0
//     (L1-hot), so   sum_valid = sum_all - (10 - cnt) * row0_frag.
//     mm[] dies immediately after the offset cndmask phase.
__global__ __launch_bounds__(256, 8) void emb_fwd_kernel(
    const int*   __restrict__ keys,   // [ROWS, MAX_NNZ]
    const int*   __restrict__ mask,   // [ROWS, MAX_NNZ] (0/1)
    const float* __restrict__ table,  // [VOCAB, EMB]
    float*       __restrict__ out)    // [ROWS, EMB]
{
    int tid = blockIdx.x * blockDim.x + threadIdx.x;
    int row = tid >> 5;        // 32 lanes per row
    int e2  = tid & 31;        // which float2 of the 64-float row
    if (row >= ROWS) return;

    const int* kp = keys + row * MAX_NNZ;
    const int* mp = mask + row * MAX_NNZ;

    // Load keys+mask, fold mask into the byte offset immediately so the
    // mask registers die before the gather phase. Masked entries redirect
    // to table row 0 (stays L1-resident).
    unsigned off[MAX_NNZ];
    int cnt = 0;
#pragma unroll
    for (int j = 0; j < MAX_NNZ; ++j) {
        int k = kp[j];
        int m = mp[j];
        cnt += (m != 0);
        off[j] = ((unsigned)(m ? k : 0)) << 8;   // row byte offset, < 2^28
    }

    const char* tb = (const char*)table;
    unsigned e8 = (unsigned)e2 * 8u;             // byte offset within row

    // Issue ALL gathers (plus the row-0 fragment) before consuming any —
    // 11 outstanding 8B loads per thread, 32-bit voffset addressing.
    floatx2 r0 = *(const floatx2*)(tb + e8);     // row 0 fragment, L1-hot
    floatx2 v[MAX_NNZ];
#pragma unroll
    for (int j = 0; j < MAX_NNZ; ++j) {
        v[j] = *(const floatx2*)(tb + (off[j] + e8));
    }

    // Tree-sum of all 10 fragments (masked ones contributed row0 values).
    floatx2 s01 = v[0] + v[1];
    floatx2 s23 = v[2] + v[3];
    floatx2 s45 = v[4] + v[5];
    floatx2 s67 = v[6] + v[7];
    floatx2 s89 = v[8] + v[9];
    floatx2 acc = ((s01 + s23) + (s45 + s67)) + s89;

    // Remove the masked (row-0) contributions, then mean-combine.
    float miss = (float)(MAX_NNZ - cnt);
    float inv  = 1.0f / (float)(cnt > 0 ? cnt : 1);
    acc = (acc - miss * r0) * inv;

    // Streaming store — output has no reuse; keep L2/L3 for the table.
    floatx2* op = (floatx2*)(out + (size_t)row * EMB) + e2;
    __builtin_nontemporal_store(acc, op);
}

extern "C" void kernel_launch(void* const* d_in, const int* in_sizes, int n_in,
                              void* d_out, int out_size, void* d_ws, size_t ws_size,
                              hipStream_t stream) {
    const int*   keys  = (const int*)d_in[0];
    const int*   mask  = (const int*)d_in[1];
    const float* table = (const float*)d_in[2];
    float*       out   = (float*)d_out;

    const int threads_per_row = 32;
    const int block = 256;
    const long long total_threads = (long long)ROWS * threads_per_row;
    const int grid = (int)((total_threads + block - 1) / block);   // 13312 blocks

    emb_fwd_kernel<<<grid, block, 0, stream>>>(keys, mask, table, out);
}